// Round 2
// baseline (258.999 us; speedup 1.0000x reference)
//
#include <hip/hip_runtime.h>

#define N_NODES 100000
#define N_EDGES 1600000
#define B2_SHIFT 9
#define BUCK_N (1 << B2_SHIFT)                   // 512 nodes per bucket
#define NB2 ((N_NODES + BUCK_N - 1) >> B2_SHIFT) // 196 buckets
#define BCAP 9216                                // padded bucket capacity (avg 8163)
#define PAIR_EPB 4096
#define PAIR_BLOCKS ((N_EDGES + PAIR_EPB - 1) / PAIR_EPB)   // 391
#define CAST_BLOCKS 6250                         // 16N threads, float4 each
#define PREP_BLOCKS (PAIR_BLOCKS + 1 + CAST_BLOCKS)

typedef __attribute__((ext_vector_type(8))) short bf16x8;
typedef __attribute__((ext_vector_type(4))) float f32x4;

// ---- bf16 pack/unpack helpers (RNE) ----
__device__ __forceinline__ unsigned pack2(float a, float b) {
    unsigned ua = __float_as_uint(a), ub = __float_as_uint(b);
    ua = (ua + 0x7FFFu + ((ua >> 16) & 1u)) >> 16;
    ub = (ub + 0x7FFFu + ((ub >> 16) & 1u)) >> 16;
    return ua | (ub << 16);
}
__device__ __forceinline__ float lo16(unsigned u) { return __uint_as_float(u << 16); }
__device__ __forceinline__ float hi16(unsigned u) { return __uint_as_float(u & 0xFFFF0000u); }

// ============ fused prep: pairs-bucketing | weight-frag build | x cast =====
__global__ __launch_bounds__(256) void k_prep(
    const float* __restrict__ x, const int* __restrict__ ei,
    const float* __restrict__ W1l, const float* __restrict__ W1r,
    const float* __restrict__ W2l, const float* __restrict__ W2r,
    unsigned* __restrict__ xh, int* __restrict__ bcur,
    int* __restrict__ pairs, uint4* __restrict__ wf)
{
    __shared__ int lh[2][NB2];
    __shared__ int lb[2][NB2];

    if (blockIdx.x < PAIR_BLOCKS) {
        // ---- edge bucketing: (src<<9)|(dst&511) into padded bucket regions
        for (int i = threadIdx.x; i < NB2; i += 256) { lh[0][i] = 0; lh[1][i] = 0; }
        __syncthreads();
        int cp = (threadIdx.x >> 6) & 1;          // wave-pair copy
        int base = blockIdx.x * PAIR_EPB;
        int myb[16], myr[16], myp[16];
#pragma unroll
        for (int t = 0; t < 16; t++) {
            int e = base + t * 256 + threadIdx.x;
            myb[t] = -1;
            if (e < N_EDGES) {
                int dst = ei[N_EDGES + e];
                int b = dst >> B2_SHIFT;
                myb[t] = b;
                myr[t] = atomicAdd(&lh[cp][b], 1);
                myp[t] = (ei[e] << B2_SHIFT) | (dst & (BUCK_N - 1));
            }
        }
        __syncthreads();
        for (int i = threadIdx.x; i < NB2; i += 256) {
            int c0 = lh[0][i], c1 = lh[1][i];
            int basei = (c0 + c1) ? atomicAdd(&bcur[i], c0 + c1) : 0;
            lb[0][i] = basei;
            lb[1][i] = basei + c0;
        }
        __syncthreads();
#pragma unroll
        for (int t = 0; t < 16; t++) {
            if (myb[t] >= 0) {
                int slot = lb[cp][myb[t]] + myr[t];
                if (slot < BCAP)                  // defensive (never expected)
                    pairs[myb[t] * BCAP + slot] = myp[t];
            }
        }
    } else if (blockIdx.x == PAIR_BLOCKS) {
        // ---- build B-fragments once: frag f, lane l holds B[k0..k0+7][j]
        for (int s = threadIdx.x; s < 1536; s += 256) {
            int f = s >> 6, l = s & 63;
            int m = l & 15, q = l >> 4;
            float w[8];
            if (f < 16) {                         // B1 = [W1l(k<64); W1r(k>=64)]
                int jt = f >> 2, ks = f & 3;
                int j = jt * 16 + m;
                int k0 = ks * 32 + q * 8;
#pragma unroll
                for (int i = 0; i < 8; i++) {
                    int kk = k0 + i;
                    w[i] = (kk < 64) ? W1l[kk * 64 + j] : W1r[(kk - 64) * 64 + j];
                }
            } else {                              // B2 = [W2l | W2r]
                int f2 = f - 16;
                int jt = f2 >> 1, ks = f2 & 1;
                int j = jt * 16 + m;
                int k0 = ks * 32 + q * 8;
#pragma unroll
                for (int i = 0; i < 8; i++) {
                    int kk = k0 + i;
                    w[i] = (j < 32) ? W2l[kk * 32 + j] : W2r[kk * 32 + (j - 32)];
                }
            }
            wf[s] = make_uint4(pack2(w[0], w[1]), pack2(w[2], w[3]),
                               pack2(w[4], w[5]), pack2(w[6], w[7]));
        }
    } else {
        // ---- cast x -> packed bf16 (dims pair-packed), float4 per thread
        int i = (blockIdx.x - PAIR_BLOCKS - 1) * 256 + threadIdx.x;  // over 16N
        if (i < N_NODES * 16) {
            float4 v = ((const float4*)x)[i];
            ((uint2*)xh)[i] = make_uint2(pack2(v.x, v.y), pack2(v.z, v.w));
        }
    }
}

// ============ per-bucket CSR finalize: LDS-staged hist + scan + scatter ====
__global__ __launch_bounds__(512) void k_sortb(const int* __restrict__ bcur,
                                               const int* __restrict__ pairs,
                                               int* __restrict__ sorted_src,
                                               int* __restrict__ rs,
                                               int* __restrict__ re)
{
    __shared__ int sp[BCAP];      // 36 KB: this bucket's pairs, staged once
    __shared__ int lcnt[BUCK_N];
    __shared__ int wtot[8];
    int b = blockIdx.x;
    int beg = b * BCAP;
    int cnt = bcur[b];
    if (cnt > BCAP) cnt = BCAP;   // defensive
    for (int i = threadIdx.x; i < cnt; i += 512) sp[i] = pairs[beg + i];
    lcnt[threadIdx.x] = 0;
    __syncthreads();
    for (int i = threadIdx.x; i < cnt; i += 512)
        atomicAdd(&lcnt[sp[i] & (BUCK_N - 1)], 1);
    __syncthreads();
    int v = lcnt[threadIdx.x];
    // wave-level inclusive scan (64 lanes, no barriers)
    int lane = threadIdx.x & 63, wid = threadIdx.x >> 6;
    int s = v;
#pragma unroll
    for (int off = 1; off < 64; off <<= 1) {
        int t = __shfl_up(s, off);
        if (lane >= off) s += t;
    }
    if (lane == 63) wtot[wid] = s;
    __syncthreads();
    // cross-wave exclusive offset (8 values, done redundantly per thread)
    int woff = 0;
#pragma unroll
    for (int k = 0; k < 8; k++) woff += (k < wid) ? wtot[k] : 0;
    int excl = woff + s - v;
    int n = (b << B2_SHIFT) + threadIdx.x;
    if (n < N_NODES) { rs[n] = beg + excl; re[n] = beg + excl + v; }
    __syncthreads();
    lcnt[threadIdx.x] = beg + excl;           // global write cursor
    __syncthreads();
    for (int i = threadIdx.x; i < cnt; i += 512) {
        int p = sp[i];
        int idx = atomicAdd(&lcnt[p & (BUCK_N - 1)], 1);
        sorted_src[idx] = p >> B2_SHIFT;
    }
}

// ============ fused agg1 + node transform via MFMA ============
// One wave per 16-node tile: gather-sum neighbor xh rows (agg1, in-register,
// staged to LDS), then layer1 MFMA + ReLU + layer2 MFMA, writes t2h (bf16)
// and t3 (+b2l, f32). No barriers in the tile loop -> waves free-run, gather
// VMEM overlaps other waves' MFMA.
#define TPW 2     // tiles per wave
#define NTILE ((N_NODES + 15) / 16)                    // 6250
#define NODE_BLOCKS (((NTILE + TPW - 1) / TPW + 3) / 4)  // 782
__global__ __launch_bounds__(256) void k_node_mfma(
    const unsigned* __restrict__ xh,
    const int* __restrict__ rs, const int* __restrict__ re,
    const int* __restrict__ sorted_src,
    const float* __restrict__ b1l, const float* __restrict__ b2l,
    const uint4* __restrict__ wf,
    unsigned* __restrict__ t2h, float* __restrict__ t3)
{
    __shared__ uint4 sWF[24 * 64];        // weight B-fragments, 24 KB
    __shared__ float sH[4][16 * 68];      // per-wave agg/h buffer (pad 68)
    __shared__ float sT[4][16 * 44];      // per-wave t2 stage (pad 44)

    // ---- coalesced load of precomputed B-fragments (16 B/lane) ----
    for (int s = threadIdx.x; s < 1536; s += 256)
        sWF[s] = wf[s];
    __syncthreads();

    int w = threadIdx.x >> 6, lane = threadIdx.x & 63;
    int m = lane & 15, q = lane >> 4;
    int half = lane >> 5, d2g = lane & 31;   // gather mapping: 32 lanes/node

    float bias[4];
#pragma unroll
    for (int jt = 0; jt < 4; jt++) bias[jt] = b1l[jt * 16 + m];
    float bias2[2] = { b2l[m], b2l[16 + m] };

    float* myH = &sH[w][0];
    float* myT = &sT[w][0];
    int gw = blockIdx.x * 4 + w;

    for (int t = 0; t < TPW; t++) {
        int tile = gw * TPW + t;
        if (tile >= NTILE) break;
        int nb = tile * 16;

        // ---- fused agg1: gather-sum xh rows for this tile's 16 nodes ----
        for (int p = 0; p < 8; p++) {
            int node = nb + 2 * p + half;
            float a0 = 0.f, a1 = 0.f, c0 = 0.f, c1 = 0.f;
            if (node < N_NODES) {
                int beg = rs[node], end = re[node];
                int idx = beg;
                for (; idx + 8 <= end; idx += 8) {
                    int s0 = sorted_src[idx + 0], s1 = sorted_src[idx + 1];
                    int s2 = sorted_src[idx + 2], s3 = sorted_src[idx + 3];
                    int s4 = sorted_src[idx + 4], s5 = sorted_src[idx + 5];
                    int s6 = sorted_src[idx + 6], s7 = sorted_src[idx + 7];
                    unsigned p0 = xh[(size_t)s0 * 32 + d2g];
                    unsigned p1 = xh[(size_t)s1 * 32 + d2g];
                    unsigned p2 = xh[(size_t)s2 * 32 + d2g];
                    unsigned p3 = xh[(size_t)s3 * 32 + d2g];
                    unsigned p4 = xh[(size_t)s4 * 32 + d2g];
                    unsigned p5 = xh[(size_t)s5 * 32 + d2g];
                    unsigned p6 = xh[(size_t)s6 * 32 + d2g];
                    unsigned p7 = xh[(size_t)s7 * 32 + d2g];
                    a0 += lo16(p0) + lo16(p1);  a1 += hi16(p0) + hi16(p1);
                    c0 += lo16(p2) + lo16(p3);  c1 += hi16(p2) + hi16(p3);
                    a0 += lo16(p4) + lo16(p5);  a1 += hi16(p4) + hi16(p5);
                    c0 += lo16(p6) + lo16(p7);  c1 += hi16(p6) + hi16(p7);
                }
                for (; idx + 2 <= end; idx += 2) {
                    int s0 = sorted_src[idx], s1 = sorted_src[idx + 1];
                    unsigned p0 = xh[(size_t)s0 * 32 + d2g];
                    unsigned p1 = xh[(size_t)s1 * 32 + d2g];
                    a0 += lo16(p0) + lo16(p1);  a1 += hi16(p0) + hi16(p1);
                }
                if (idx < end) {
                    unsigned p0 = xh[(size_t)sorted_src[idx] * 32 + d2g];
                    a0 += lo16(p0);  a1 += hi16(p0);
                }
            }
            *(float2*)&myH[(2 * p + half) * 68 + 2 * d2g] =
                make_float2(a0 + c0, a1 + c1);
        }
        // wave-synchronous: same wave wrote myH, now reads fragments

        // ---- A-fragments: agg (from LDS) and x (from global) ----
        int nc = nb + m; if (nc >= N_NODES) nc = N_NODES - 1;
        bf16x8 AM[2], AX[2];
#pragma unroll
        for (int ks = 0; ks < 2; ks++) {
            const float* pH = &myH[m * 68 + ks * 32 + q * 8];
            float4 v0 = *(const float4*)pH;
            float4 v1 = *(const float4*)(pH + 4);
            uint4 u = make_uint4(pack2(v0.x, v0.y), pack2(v0.z, v0.w),
                                 pack2(v1.x, v1.y), pack2(v1.z, v1.w));
            AM[ks] = __builtin_bit_cast(bf16x8, u);
        }
        const uint4* xrow = (const uint4*)(xh + (size_t)nc * 32);
        AX[0] = __builtin_bit_cast(bf16x8, xrow[q]);
        AX[1] = __builtin_bit_cast(bf16x8, xrow[4 + q]);

        float invr[4];
#pragma unroll
        for (int r = 0; r < 4; r++) {
            int nn = nb + q * 4 + r;
            int nc2 = (nn < N_NODES) ? nn : 0;
            invr[r] = 1.0f / fmaxf((float)(re[nc2] - rs[nc2]), 1.0f);
        }

        // ---- layer 1 (weight frags consumed straight from LDS) ----
#pragma unroll
        for (int jt = 0; jt < 4; jt++) {
            f32x4 aM = {0.f, 0.f, 0.f, 0.f}, aX = {0.f, 0.f, 0.f, 0.f};
            aM = __builtin_amdgcn_mfma_f32_16x16x32_bf16(
                AM[0], __builtin_bit_cast(bf16x8, sWF[(jt * 4 + 0) * 64 + lane]), aM, 0, 0, 0);
            aM = __builtin_amdgcn_mfma_f32_16x16x32_bf16(
                AM[1], __builtin_bit_cast(bf16x8, sWF[(jt * 4 + 1) * 64 + lane]), aM, 0, 0, 0);
            aX = __builtin_amdgcn_mfma_f32_16x16x32_bf16(
                AX[0], __builtin_bit_cast(bf16x8, sWF[(jt * 4 + 2) * 64 + lane]), aX, 0, 0, 0);
            aX = __builtin_amdgcn_mfma_f32_16x16x32_bf16(
                AX[1], __builtin_bit_cast(bf16x8, sWF[(jt * 4 + 3) * 64 + lane]), aX, 0, 0, 0);
#pragma unroll
            for (int r = 0; r < 4; r++) {
                float hv = fmaxf(aM[r] * invr[r] + aX[r] + bias[jt], 0.0f);
                myH[(q * 4 + r) * 68 + jt * 16 + m] = hv;   // [node][j]
            }
        }
        // wave-synchronous LDS round-trip (same wave writes then reads)

        bf16x8 A2[2];
#pragma unroll
        for (int ks = 0; ks < 2; ks++) {
            const float* p = &myH[m * 68 + ks * 32 + q * 8];
            float4 v0 = *(const float4*)p;
            float4 v1 = *(const float4*)(p + 4);
            uint4 u = make_uint4(pack2(v0.x, v0.y), pack2(v0.z, v0.w),
                                 pack2(v1.x, v1.y), pack2(v1.z, v1.w));
            A2[ks] = __builtin_bit_cast(bf16x8, u);
        }

        // ---- layer 2 ----
#pragma unroll
        for (int jt = 0; jt < 4; jt++) {
            f32x4 acc = {0.f, 0.f, 0.f, 0.f};
            acc = __builtin_amdgcn_mfma_f32_16x16x32_bf16(
                A2[0], __builtin_bit_cast(bf16x8, sWF[(16 + jt * 2 + 0) * 64 + lane]), acc, 0, 0, 0);
            acc = __builtin_amdgcn_mfma_f32_16x16x32_bf16(
                A2[1], __builtin_bit_cast(bf16x8, sWF[(16 + jt * 2 + 1) * 64 + lane]), acc, 0, 0, 0);
            if (jt < 2) {
#pragma unroll
                for (int r = 0; r < 4; r++)
                    myT[(q * 4 + r) * 44 + jt * 16 + m] = acc[r];
            } else {
#pragma unroll
                for (int r = 0; r < 4; r++) {
                    int nn = nb + q * 4 + r;
                    if (nn < N_NODES)
                        t3[(size_t)nn * 32 + (jt - 2) * 16 + m] = acc[r] + bias2[jt - 2];
                }
            }
        }

        // ---- pack t2 -> bf16 global (4 lanes per node) ----
        int ni = lane >> 2, u4g = lane & 3;
        const float* tp = &myT[ni * 44 + u4g * 8];
        float4 a = *(const float4*)tp;
        float4 b = *(const float4*)(tp + 4);
        if (nb + ni < N_NODES) {
            uint4 o = make_uint4(pack2(a.x, a.y), pack2(a.z, a.w),
                                 pack2(b.x, b.y), pack2(b.z, b.w));
            *(uint4*)(t2h + (size_t)(nb + ni) * 16 + u4g * 4) = o;
        }
    }
}

// ============ agg2 + output: 16 lanes/node, bf16 gather, 8-deep unroll =====
__global__ __launch_bounds__(256) void k_agg2out(
    const int* __restrict__ rs, const int* __restrict__ re,
    const int* __restrict__ sorted_src,
    const unsigned* __restrict__ t2h, const float* __restrict__ t3,
    float* __restrict__ out)
{
    int node = blockIdx.x * 16 + (threadIdx.x >> 4);
    if (node >= N_NODES) return;
    int d2 = threadIdx.x & 15;       // dims 2*d2, 2*d2+1
    int beg = rs[node], end = re[node];
    float a0 = 0.f, a1 = 0.f, b0 = 0.f, b1 = 0.f;
    int idx = beg;
    for (; idx + 8 <= end; idx += 8) {
        int s0 = sorted_src[idx + 0], s1 = sorted_src[idx + 1];
        int s2 = sorted_src[idx + 2], s3 = sorted_src[idx + 3];
        int s4 = sorted_src[idx + 4], s5 = sorted_src[idx + 5];
        int s6 = sorted_src[idx + 6], s7 = sorted_src[idx + 7];
        unsigned p0 = t2h[(size_t)s0 * 16 + d2];
        unsigned p1 = t2h[(size_t)s1 * 16 + d2];
        unsigned p2 = t2h[(size_t)s2 * 16 + d2];
        unsigned p3 = t2h[(size_t)s3 * 16 + d2];
        unsigned p4 = t2h[(size_t)s4 * 16 + d2];
        unsigned p5 = t2h[(size_t)s5 * 16 + d2];
        unsigned p6 = t2h[(size_t)s6 * 16 + d2];
        unsigned p7 = t2h[(size_t)s7 * 16 + d2];
        a0 += lo16(p0) + lo16(p1);  a1 += hi16(p0) + hi16(p1);
        b0 += lo16(p2) + lo16(p3);  b1 += hi16(p2) + hi16(p3);
        a0 += lo16(p4) + lo16(p5);  a1 += hi16(p4) + hi16(p5);
        b0 += lo16(p6) + lo16(p7);  b1 += hi16(p6) + hi16(p7);
    }
    for (; idx + 2 <= end; idx += 2) {
        int s0 = sorted_src[idx], s1 = sorted_src[idx + 1];
        unsigned p0 = t2h[(size_t)s0 * 16 + d2];
        unsigned p1 = t2h[(size_t)s1 * 16 + d2];
        a0 += lo16(p0) + lo16(p1);  a1 += hi16(p0) + hi16(p1);
    }
    if (idx < end) {
        unsigned p = t2h[(size_t)sorted_src[idx] * 16 + d2];
        a0 += lo16(p);  a1 += hi16(p);
    }
    float inv = 1.0f / fmaxf((float)(end - beg), 1.0f);
    float2 tv = ((const float2*)(t3 + (size_t)node * 32))[d2];
    ((float2*)(out + (size_t)node * 32))[d2] =
        make_float2((a0 + b0) * inv + tv.x,
                    (a1 + b1) * inv + tv.y);
}

extern "C" void kernel_launch(void* const* d_in, const int* in_sizes, int n_in,
                              void* d_out, int out_size, void* d_ws, size_t ws_size,
                              hipStream_t stream) {
    const float* x   = (const float*)d_in[0];
    const int*   ei  = (const int*)d_in[1];
    const float* W1l = (const float*)d_in[2];
    const float* b1l = (const float*)d_in[3];
    const float* W1r = (const float*)d_in[4];
    const float* W2l = (const float*)d_in[5];
    const float* b2l = (const float*)d_in[6];
    const float* W2r = (const float*)d_in[7];
    float* out = (float*)d_out;

    const size_t N = N_NODES;
    // 64 B-aligned workspace layout
    int* wsi = (int*)d_ws;
    int*      pairs      = wsi;                          // NB2*BCAP = 1806336
    int*      sorted_src = wsi + 1806336;                // NB2*BCAP
    int*      bcur       = wsi + 3612672;                // 256
    int*      rs         = wsi + 3612928;                // N
    int*      re         = wsi + 3712928;                // N
    unsigned* xh         = (unsigned*)(wsi + 3812928);   // 32N
    unsigned* t2h        = xh + 32 * N;                  // 16N
    float*    t3         = (float*)(t2h + 16 * N);       // 32N
    uint4*    wf         = (uint4*)(t3 + 32 * N);        // 1536 uint4 = 24 KB

    hipMemsetAsync(bcur, 0, NB2 * sizeof(int), stream);
    k_prep <<<PREP_BLOCKS, 256, 0, stream>>>(x, ei, W1l, W1r, W2l, W2r,
                                             xh, bcur, pairs, wf);
    k_sortb<<<NB2, 512, 0, stream>>>(bcur, pairs, sorted_src, rs, re);

    k_node_mfma<<<NODE_BLOCKS, 256, 0, stream>>>(xh, rs, re, sorted_src,
                                                 b1l, b2l, wf, t2h, t3);
    k_agg2out  <<<(int)((N + 15) / 16), 256, 0, stream>>>(rs, re, sorted_src,
                                                 t2h, t3, out);
}

// Round 3
// 191.185 us; speedup vs baseline: 1.3547x; 1.3547x over previous
//
#include <hip/hip_runtime.h>

#define N_NODES 100000
#define N_EDGES 1600000
#define B2_SHIFT 9
#define BUCK_N (1 << B2_SHIFT)                   // 512 nodes per bucket
#define NB2 ((N_NODES + BUCK_N - 1) >> B2_SHIFT) // 196 buckets
#define BCAP 9216                                // padded bucket capacity (avg 8163)
#define PAIR_EPB 4096
#define PAIR_BLOCKS ((N_EDGES + PAIR_EPB - 1) / PAIR_EPB)   // 391
#define CAST_BLOCKS 6250                         // 16N threads, float4 each
#define PREP_BLOCKS (PAIR_BLOCKS + 1 + CAST_BLOCKS)

typedef __attribute__((ext_vector_type(8))) short bf16x8;
typedef __attribute__((ext_vector_type(4))) float f32x4;

// ---- bf16 pack/unpack helpers (RNE) ----
__device__ __forceinline__ unsigned pack2(float a, float b) {
    unsigned ua = __float_as_uint(a), ub = __float_as_uint(b);
    ua = (ua + 0x7FFFu + ((ua >> 16) & 1u)) >> 16;
    ub = (ub + 0x7FFFu + ((ub >> 16) & 1u)) >> 16;
    return ua | (ub << 16);
}
__device__ __forceinline__ float lo16(unsigned u) { return __uint_as_float(u << 16); }
__device__ __forceinline__ float hi16(unsigned u) { return __uint_as_float(u & 0xFFFF0000u); }

// ============ fused prep: pairs-bucketing | weight-frag build | x cast =====
__global__ __launch_bounds__(256) void k_prep(
    const float* __restrict__ x, const int* __restrict__ ei,
    const float* __restrict__ W1l, const float* __restrict__ W1r,
    const float* __restrict__ W2l, const float* __restrict__ W2r,
    unsigned* __restrict__ xh, int* __restrict__ bcur,
    int* __restrict__ pairs, uint4* __restrict__ wf)
{
    __shared__ int lh[2][NB2];
    __shared__ int lb[2][NB2];

    if (blockIdx.x < PAIR_BLOCKS) {
        // ---- edge bucketing: (src<<9)|(dst&511) into padded bucket regions
        for (int i = threadIdx.x; i < NB2; i += 256) { lh[0][i] = 0; lh[1][i] = 0; }
        __syncthreads();
        int cp = (threadIdx.x >> 6) & 1;          // wave-pair copy
        int base = blockIdx.x * PAIR_EPB;
        int myb[16], myr[16], myp[16];
#pragma unroll
        for (int t = 0; t < 16; t++) {
            int e = base + t * 256 + threadIdx.x;
            myb[t] = -1;
            if (e < N_EDGES) {
                int dst = ei[N_EDGES + e];
                int b = dst >> B2_SHIFT;
                myb[t] = b;
                myr[t] = atomicAdd(&lh[cp][b], 1);
                myp[t] = (ei[e] << B2_SHIFT) | (dst & (BUCK_N - 1));
            }
        }
        __syncthreads();
        for (int i = threadIdx.x; i < NB2; i += 256) {
            int c0 = lh[0][i], c1 = lh[1][i];
            int basei = (c0 + c1) ? atomicAdd(&bcur[i], c0 + c1) : 0;
            lb[0][i] = basei;
            lb[1][i] = basei + c0;
        }
        __syncthreads();
#pragma unroll
        for (int t = 0; t < 16; t++) {
            if (myb[t] >= 0) {
                int slot = lb[cp][myb[t]] + myr[t];
                if (slot < BCAP)                  // defensive (never expected)
                    pairs[myb[t] * BCAP + slot] = myp[t];
            }
        }
    } else if (blockIdx.x == PAIR_BLOCKS) {
        // ---- build B-fragments once: frag f, lane l holds B[k0..k0+7][j]
        for (int s = threadIdx.x; s < 1536; s += 256) {
            int f = s >> 6, l = s & 63;
            int m = l & 15, q = l >> 4;
            float w[8];
            if (f < 16) {                         // B1 = [W1l(k<64); W1r(k>=64)]
                int jt = f >> 2, ks = f & 3;
                int j = jt * 16 + m;
                int k0 = ks * 32 + q * 8;
#pragma unroll
                for (int i = 0; i < 8; i++) {
                    int kk = k0 + i;
                    w[i] = (kk < 64) ? W1l[kk * 64 + j] : W1r[(kk - 64) * 64 + j];
                }
            } else {                              // B2 = [W2l | W2r]
                int f2 = f - 16;
                int jt = f2 >> 1, ks = f2 & 1;
                int j = jt * 16 + m;
                int k0 = ks * 32 + q * 8;
#pragma unroll
                for (int i = 0; i < 8; i++) {
                    int kk = k0 + i;
                    w[i] = (j < 32) ? W2l[kk * 32 + j] : W2r[kk * 32 + (j - 32)];
                }
            }
            wf[s] = make_uint4(pack2(w[0], w[1]), pack2(w[2], w[3]),
                               pack2(w[4], w[5]), pack2(w[6], w[7]));
        }
    } else {
        // ---- cast x -> packed bf16 (dims pair-packed), float4 per thread
        int i = (blockIdx.x - PAIR_BLOCKS - 1) * 256 + threadIdx.x;  // over 16N
        if (i < N_NODES * 16) {
            float4 v = ((const float4*)x)[i];
            ((uint2*)xh)[i] = make_uint2(pack2(v.x, v.y), pack2(v.z, v.w));
        }
    }
}

// ============ per-bucket CSR finalize: LDS-staged hist + scan + scatter ====
__global__ __launch_bounds__(512) void k_sortb(const int* __restrict__ bcur,
                                               const int* __restrict__ pairs,
                                               int* __restrict__ sorted_src,
                                               int* __restrict__ rs,
                                               int* __restrict__ re)
{
    __shared__ int sp[BCAP];      // 36 KB: this bucket's pairs, staged once
    __shared__ int lcnt[BUCK_N];
    __shared__ int wtot[8];
    int b = blockIdx.x;
    int beg = b * BCAP;
    int cnt = bcur[b];
    if (cnt > BCAP) cnt = BCAP;   // defensive
    for (int i = threadIdx.x; i < cnt; i += 512) sp[i] = pairs[beg + i];
    lcnt[threadIdx.x] = 0;
    __syncthreads();
    for (int i = threadIdx.x; i < cnt; i += 512)
        atomicAdd(&lcnt[sp[i] & (BUCK_N - 1)], 1);
    __syncthreads();
    int v = lcnt[threadIdx.x];
    // wave-level inclusive scan (64 lanes, no barriers)
    int lane = threadIdx.x & 63, wid = threadIdx.x >> 6;
    int s = v;
#pragma unroll
    for (int off = 1; off < 64; off <<= 1) {
        int t = __shfl_up(s, off);
        if (lane >= off) s += t;
    }
    if (lane == 63) wtot[wid] = s;
    __syncthreads();
    // cross-wave exclusive offset (8 values, done redundantly per thread)
    int woff = 0;
#pragma unroll
    for (int k = 0; k < 8; k++) woff += (k < wid) ? wtot[k] : 0;
    int excl = woff + s - v;
    int n = (b << B2_SHIFT) + threadIdx.x;
    if (n < N_NODES) { rs[n] = beg + excl; re[n] = beg + excl + v; }
    __syncthreads();
    lcnt[threadIdx.x] = beg + excl;           // global write cursor
    __syncthreads();
    for (int i = threadIdx.x; i < cnt; i += 512) {
        int p = sp[i];
        int idx = atomicAdd(&lcnt[p & (BUCK_N - 1)], 1);
        sorted_src[idx] = p >> B2_SHIFT;
    }
}

// ============ agg1: 16 lanes/node, uint2 (8B) gather, 8-deep unroll ========
__global__ __launch_bounds__(256) void k_agg1(const int* __restrict__ rs,
                                              const int* __restrict__ re,
                                              const int* __restrict__ sorted_src,
                                              const unsigned* __restrict__ xh,
                                              unsigned* __restrict__ agg1h)
{
    int node = blockIdx.x * 16 + (threadIdx.x >> 4);
    if (node >= N_NODES) return;
    int d4 = threadIdx.x & 15;       // dims 4*d4 .. 4*d4+3
    const uint2* xh2 = (const uint2*)xh;
    int beg = rs[node], end = re[node];
    float a0 = 0.f, a1 = 0.f, a2 = 0.f, a3 = 0.f;
    float b0 = 0.f, b1 = 0.f, b2 = 0.f, b3 = 0.f;
    int idx = beg;
    for (; idx + 8 <= end; idx += 8) {
        int s0 = sorted_src[idx + 0], s1 = sorted_src[idx + 1];
        int s2 = sorted_src[idx + 2], s3 = sorted_src[idx + 3];
        int s4 = sorted_src[idx + 4], s5 = sorted_src[idx + 5];
        int s6 = sorted_src[idx + 6], s7 = sorted_src[idx + 7];
        uint2 p0 = xh2[(size_t)s0 * 16 + d4];
        uint2 p1 = xh2[(size_t)s1 * 16 + d4];
        uint2 p2 = xh2[(size_t)s2 * 16 + d4];
        uint2 p3 = xh2[(size_t)s3 * 16 + d4];
        uint2 p4 = xh2[(size_t)s4 * 16 + d4];
        uint2 p5 = xh2[(size_t)s5 * 16 + d4];
        uint2 p6 = xh2[(size_t)s6 * 16 + d4];
        uint2 p7 = xh2[(size_t)s7 * 16 + d4];
        a0 += lo16(p0.x) + lo16(p1.x);  a1 += hi16(p0.x) + hi16(p1.x);
        a2 += lo16(p0.y) + lo16(p1.y);  a3 += hi16(p0.y) + hi16(p1.y);
        b0 += lo16(p2.x) + lo16(p3.x);  b1 += hi16(p2.x) + hi16(p3.x);
        b2 += lo16(p2.y) + lo16(p3.y);  b3 += hi16(p2.y) + hi16(p3.y);
        a0 += lo16(p4.x) + lo16(p5.x);  a1 += hi16(p4.x) + hi16(p5.x);
        a2 += lo16(p4.y) + lo16(p5.y);  a3 += hi16(p4.y) + hi16(p5.y);
        b0 += lo16(p6.x) + lo16(p7.x);  b1 += hi16(p6.x) + hi16(p7.x);
        b2 += lo16(p6.y) + lo16(p7.y);  b3 += hi16(p6.y) + hi16(p7.y);
    }
    for (; idx + 2 <= end; idx += 2) {
        int s0 = sorted_src[idx], s1 = sorted_src[idx + 1];
        uint2 p0 = xh2[(size_t)s0 * 16 + d4];
        uint2 p1 = xh2[(size_t)s1 * 16 + d4];
        a0 += lo16(p0.x) + lo16(p1.x);  a1 += hi16(p0.x) + hi16(p1.x);
        a2 += lo16(p0.y) + lo16(p1.y);  a3 += hi16(p0.y) + hi16(p1.y);
    }
    if (idx < end) {
        uint2 p = xh2[(size_t)sorted_src[idx] * 16 + d4];
        a0 += lo16(p.x);  a1 += hi16(p.x);
        a2 += lo16(p.y);  a3 += hi16(p.y);
    }
    ((uint2*)agg1h)[(size_t)node * 16 + d4] =
        make_uint2(pack2(a0 + b0, a1 + b1), pack2(a2 + b2, a3 + b3));
}

// ============ node transform via MFMA: one wave per 16-node tile ============
#define TPW 2     // tiles per wave
#define NTILE ((N_NODES + 15) / 16)                    // 6250
#define NODE_BLOCKS (((NTILE + TPW - 1) / TPW + 3) / 4)  // 782
__global__ __launch_bounds__(256) void k_node_mfma(
    const unsigned* __restrict__ xh, const unsigned* __restrict__ agg1h,
    const int* __restrict__ rs, const int* __restrict__ re,
    const float* __restrict__ b1l, const float* __restrict__ b2l,
    const uint4* __restrict__ wf,
    unsigned* __restrict__ t2h, float* __restrict__ t3)
{
    __shared__ uint4 sWF[24 * 64];        // weight B-fragments, 24 KB
    __shared__ float sH[4][16 * 68];      // per-wave h buffer (pad 68)
    __shared__ float sT[4][16 * 44];      // per-wave t2 stage (pad 44)

    // ---- coalesced load of precomputed B-fragments (16 B/lane) ----
    for (int s = threadIdx.x; s < 1536; s += 256)
        sWF[s] = wf[s];
    __syncthreads();

    int w = threadIdx.x >> 6, lane = threadIdx.x & 63;
    int m = lane & 15, q = lane >> 4;

    bf16x8 WF1[4][4], WF2[4][2];
#pragma unroll
    for (int jt = 0; jt < 4; jt++) {
#pragma unroll
        for (int ks = 0; ks < 4; ks++)
            WF1[jt][ks] = __builtin_bit_cast(bf16x8, sWF[(jt * 4 + ks) * 64 + lane]);
#pragma unroll
        for (int ks = 0; ks < 2; ks++)
            WF2[jt][ks] = __builtin_bit_cast(bf16x8, sWF[(16 + jt * 2 + ks) * 64 + lane]);
    }
    float bias[4];
#pragma unroll
    for (int jt = 0; jt < 4; jt++) bias[jt] = b1l[jt * 16 + m];
    float bias2[2] = { b2l[m], b2l[16 + m] };

    float* myH = &sH[w][0];
    float* myT = &sT[w][0];
    int gw = blockIdx.x * 4 + w;

    for (int t = 0; t < TPW; t++) {
        int tile = gw * TPW + t;
        if (tile >= NTILE) break;
        int nb = tile * 16;

        int nc = nb + m; if (nc >= N_NODES) nc = N_NODES - 1;
        const uint4* arow = (const uint4*)(agg1h + (size_t)nc * 32);
        const uint4* xrow = (const uint4*)(xh + (size_t)nc * 32);
        bf16x8 AM[2], AX[2];
        AM[0] = __builtin_bit_cast(bf16x8, arow[q]);
        AM[1] = __builtin_bit_cast(bf16x8, arow[4 + q]);
        AX[0] = __builtin_bit_cast(bf16x8, xrow[q]);
        AX[1] = __builtin_bit_cast(bf16x8, xrow[4 + q]);

        float invr[4];
#pragma unroll
        for (int r = 0; r < 4; r++) {
            int nn = nb + q * 4 + r;
            int nc2 = (nn < N_NODES) ? nn : 0;
            invr[r] = 1.0f / fmaxf((float)(re[nc2] - rs[nc2]), 1.0f);
        }

        // ---- layer 1 ----
#pragma unroll
        for (int jt = 0; jt < 4; jt++) {
            f32x4 aM = {0.f, 0.f, 0.f, 0.f}, aX = {0.f, 0.f, 0.f, 0.f};
            aM = __builtin_amdgcn_mfma_f32_16x16x32_bf16(AM[0], WF1[jt][0], aM, 0, 0, 0);
            aM = __builtin_amdgcn_mfma_f32_16x16x32_bf16(AM[1], WF1[jt][1], aM, 0, 0, 0);
            aX = __builtin_amdgcn_mfma_f32_16x16x32_bf16(AX[0], WF1[jt][2], aX, 0, 0, 0);
            aX = __builtin_amdgcn_mfma_f32_16x16x32_bf16(AX[1], WF1[jt][3], aX, 0, 0, 0);
#pragma unroll
            for (int r = 0; r < 4; r++) {
                float hv = fmaxf(aM[r] * invr[r] + aX[r] + bias[jt], 0.0f);
                myH[(q * 4 + r) * 68 + jt * 16 + m] = hv;   // [node][j]
            }
        }
        // wave-synchronous LDS round-trip (same wave writes then reads)

        bf16x8 A2[2];
#pragma unroll
        for (int ks = 0; ks < 2; ks++) {
            const float* p = &myH[m * 68 + ks * 32 + q * 8];
            float4 v0 = *(const float4*)p;
            float4 v1 = *(const float4*)(p + 4);
            uint4 u = make_uint4(pack2(v0.x, v0.y), pack2(v0.z, v0.w),
                                 pack2(v1.x, v1.y), pack2(v1.z, v1.w));
            A2[ks] = __builtin_bit_cast(bf16x8, u);
        }

        // ---- layer 2 ----
#pragma unroll
        for (int jt = 0; jt < 4; jt++) {
            f32x4 acc = {0.f, 0.f, 0.f, 0.f};
            acc = __builtin_amdgcn_mfma_f32_16x16x32_bf16(A2[0], WF2[jt][0], acc, 0, 0, 0);
            acc = __builtin_amdgcn_mfma_f32_16x16x32_bf16(A2[1], WF2[jt][1], acc, 0, 0, 0);
            if (jt < 2) {
#pragma unroll
                for (int r = 0; r < 4; r++)
                    myT[(q * 4 + r) * 44 + jt * 16 + m] = acc[r];
            } else {
#pragma unroll
                for (int r = 0; r < 4; r++) {
                    int nn = nb + q * 4 + r;
                    if (nn < N_NODES)
                        t3[(size_t)nn * 32 + (jt - 2) * 16 + m] = acc[r] + bias2[jt - 2];
                }
            }
        }

        // ---- pack t2 -> bf16 global (4 lanes per node) ----
        int ni = lane >> 2, u4g = lane & 3;
        const float* tp = &myT[ni * 44 + u4g * 8];
        float4 a = *(const float4*)tp;
        float4 b = *(const float4*)(tp + 4);
        if (nb + ni < N_NODES) {
            uint4 o = make_uint4(pack2(a.x, a.y), pack2(a.z, a.w),
                                 pack2(b.x, b.y), pack2(b.z, b.w));
            *(uint4*)(t2h + (size_t)(nb + ni) * 16 + u4g * 4) = o;
        }
    }
}

// ============ agg2 + output: 8 lanes/node, uint2 gather, 8-deep unroll =====
__global__ __launch_bounds__(256) void k_agg2out(
    const int* __restrict__ rs, const int* __restrict__ re,
    const int* __restrict__ sorted_src,
    const unsigned* __restrict__ t2h, const float* __restrict__ t3,
    float* __restrict__ out)
{
    int node = blockIdx.x * 32 + (threadIdx.x >> 3);
    if (node >= N_NODES) return;
    int d4 = threadIdx.x & 7;        // dims 4*d4 .. 4*d4+3
    const uint2* t2 = (const uint2*)t2h;
    int beg = rs[node], end = re[node];
    float a0 = 0.f, a1 = 0.f, a2 = 0.f, a3 = 0.f;
    float b0 = 0.f, b1 = 0.f, b2 = 0.f, b3 = 0.f;
    int idx = beg;
    for (; idx + 8 <= end; idx += 8) {
        int s0 = sorted_src[idx + 0], s1 = sorted_src[idx + 1];
        int s2 = sorted_src[idx + 2], s3 = sorted_src[idx + 3];
        int s4 = sorted_src[idx + 4], s5 = sorted_src[idx + 5];
        int s6 = sorted_src[idx + 6], s7 = sorted_src[idx + 7];
        uint2 p0 = t2[(size_t)s0 * 8 + d4];
        uint2 p1 = t2[(size_t)s1 * 8 + d4];
        uint2 p2 = t2[(size_t)s2 * 8 + d4];
        uint2 p3 = t2[(size_t)s3 * 8 + d4];
        uint2 p4 = t2[(size_t)s4 * 8 + d4];
        uint2 p5 = t2[(size_t)s5 * 8 + d4];
        uint2 p6 = t2[(size_t)s6 * 8 + d4];
        uint2 p7 = t2[(size_t)s7 * 8 + d4];
        a0 += lo16(p0.x) + lo16(p1.x);  a1 += hi16(p0.x) + hi16(p1.x);
        a2 += lo16(p0.y) + lo16(p1.y);  a3 += hi16(p0.y) + hi16(p1.y);
        b0 += lo16(p2.x) + lo16(p3.x);  b1 += hi16(p2.x) + hi16(p3.x);
        b2 += lo16(p2.y) + lo16(p3.y);  b3 += hi16(p2.y) + hi16(p3.y);
        a0 += lo16(p4.x) + lo16(p5.x);  a1 += hi16(p4.x) + hi16(p5.x);
        a2 += lo16(p4.y) + lo16(p5.y);  a3 += hi16(p4.y) + hi16(p5.y);
        b0 += lo16(p6.x) + lo16(p7.x);  b1 += hi16(p6.x) + hi16(p7.x);
        b2 += lo16(p6.y) + lo16(p7.y);  b3 += hi16(p6.y) + hi16(p7.y);
    }
    for (; idx + 2 <= end; idx += 2) {
        int s0 = sorted_src[idx], s1 = sorted_src[idx + 1];
        uint2 p0 = t2[(size_t)s0 * 8 + d4];
        uint2 p1 = t2[(size_t)s1 * 8 + d4];
        a0 += lo16(p0.x) + lo16(p1.x);  a1 += hi16(p0.x) + hi16(p1.x);
        a2 += lo16(p0.y) + lo16(p1.y);  a3 += hi16(p0.y) + hi16(p1.y);
    }
    if (idx < end) {
        uint2 p = t2[(size_t)sorted_src[idx] * 8 + d4];
        a0 += lo16(p.x);  a1 += hi16(p.x);
        a2 += lo16(p.y);  a3 += hi16(p.y);
    }
    float inv = 1.0f / fmaxf((float)(end - beg), 1.0f);
    float4 tv = ((const float4*)(t3 + (size_t)node * 32))[d4];
    float4 o;
    o.x = (a0 + b0) * inv + tv.x;
    o.y = (a1 + b1) * inv + tv.y;
    o.z = (a2 + b2) * inv + tv.z;
    o.w = (a3 + b3) * inv + tv.w;
    ((float4*)(out + (size_t)node * 32))[d4] = o;
}

extern "C" void kernel_launch(void* const* d_in, const int* in_sizes, int n_in,
                              void* d_out, int out_size, void* d_ws, size_t ws_size,
                              hipStream_t stream) {
    const float* x   = (const float*)d_in[0];
    const int*   ei  = (const int*)d_in[1];
    const float* W1l = (const float*)d_in[2];
    const float* b1l = (const float*)d_in[3];
    const float* W1r = (const float*)d_in[4];
    const float* W2l = (const float*)d_in[5];
    const float* b2l = (const float*)d_in[6];
    const float* W2r = (const float*)d_in[7];
    float* out = (float*)d_out;

    const size_t N = N_NODES;
    // 64 B-aligned workspace layout
    int* wsi = (int*)d_ws;
    int*      pairs      = wsi;                          // NB2*BCAP = 1806336
    int*      sorted_src = wsi + 1806336;                // NB2*BCAP
    int*      bcur       = wsi + 3612672;                // 256
    int*      rs         = wsi + 3612928;                // N
    int*      re         = wsi + 3712928;                // N
    unsigned* xh         = (unsigned*)(wsi + 3812928);   // 32N
    unsigned* t2h        = xh + 32 * N;                  // 16N
    unsigned* agg1h      = t2h + 16 * N;                 // 32N
    float*    t3         = (float*)(agg1h + 32 * N);     // 32N
    uint4*    wf         = (uint4*)(t3 + 32 * N);        // 1536 uint4 = 24 KB

    hipMemsetAsync(bcur, 0, NB2 * sizeof(int), stream);
    k_prep <<<PREP_BLOCKS, 256, 0, stream>>>(x, ei, W1l, W1r, W2l, W2r,
                                             xh, bcur, pairs, wf);
    k_sortb<<<NB2, 512, 0, stream>>>(bcur, pairs, sorted_src, rs, re);

    k_agg1     <<<(int)((N + 15) / 16), 256, 0, stream>>>(rs, re, sorted_src, xh, agg1h);
    k_node_mfma<<<NODE_BLOCKS, 256, 0, stream>>>(xh, agg1h, rs, re,
                                                 b1l, b2l, wf, t2h, t3);
    k_agg2out  <<<(int)((N + 31) / 32), 256, 0, stream>>>(rs, re, sorted_src,
                                                 t2h, t3, out);
}